// Round 2
// baseline (368.804 us; speedup 1.0000x reference)
//
#include <hip/hip_runtime.h>
#include <math.h>

constexpr int kB = 8, kS = 1024, kD = 512, kH = 8, kHD = 64;
constexpr int kM = kB * kS; // 8192 rows

typedef __attribute__((ext_vector_type(8))) short s8v;    // 8 bf16 (A/B frag)
typedef __attribute__((ext_vector_type(4))) float f4v;    // C/D frag
typedef __attribute__((ext_vector_type(4))) unsigned short u4v;

__device__ __forceinline__ unsigned short f2bf(float f) {
    union { float f; unsigned int u; } c; c.f = f;
    unsigned int u = c.u + 0x7FFFu + ((c.u >> 16) & 1u);
    return (unsigned short)(u >> 16);
}

// async global->LDS, 16B per lane; LDS dest = wave-uniform base + lane*16
__device__ __forceinline__ void gl2lds(const unsigned short* g, unsigned short* l) {
    __builtin_amdgcn_global_load_lds(
        (const __attribute__((address_space(1))) unsigned int*)g,
        (__attribute__((address_space(3))) unsigned int*)l, 16, 0, 0);
}

// ---------------- prep: fp32->bf16 cvt (+ I folded into W1), Wo^T transpose,
//                  bo row append, AND mem softmax ----------------
// blocks [0,5120): cvt float4 segments (X, Wq, Wk, Wv, W1')
// blocks [5120,13312): mem-softmax rows
// blocks [13312,13376): Wo transpose 64x64 tiles -> WoT (bf16)
// block 13376: WoT row 512 = bo (bias column for Wcomb GEMM)
__global__ __launch_bounds__(256) void prep_kernel(
    const float* __restrict__ X, const float* __restrict__ Wq,
    const float* __restrict__ Wk, const float* __restrict__ Wv,
    const float* __restrict__ Wo, const float* __restrict__ W1,
    const float* __restrict__ ren, const float* __restrict__ ts,
    const float* __restrict__ bo_g,
    unsigned short* __restrict__ Xbf, unsigned short* __restrict__ Wqkv,
    unsigned short* __restrict__ WoT, unsigned short* __restrict__ W1bf,
    unsigned short* __restrict__ mem)
{
    __shared__ float red[4];
    const int t = threadIdx.x;
    if (blockIdx.x < 5120) {
        const int idx = blockIdx.x * 256 + t;
        const float* src; unsigned short* dst; int off; bool isw1 = false;
        if (idx < 1048576)      { src = X;  dst = Xbf;           off = idx; }
        else if (idx < 1114112) { src = Wq; dst = Wqkv;          off = idx - 1048576; }
        else if (idx < 1179648) { src = Wk; dst = Wqkv + 262144; off = idx - 1114112; }
        else if (idx < 1245184) { src = Wv; dst = Wqkv + 524288; off = idx - 1179648; }
        else                    { src = W1; dst = W1bf;          off = idx - 1245184; isw1 = true; }
        float4 v = ((const float4*)src)[off];
        if (isw1) { // fold residual: W1' = I + W1
            const int e0 = off * 4;
            const int row = e0 >> 9, col0 = e0 & 511;
            if (row >= col0 && row < col0 + 4) ((float*)&v)[row - col0] += 1.0f;
        }
        u4v p;
        p[0] = f2bf(v.x); p[1] = f2bf(v.y); p[2] = f2bf(v.z); p[3] = f2bf(v.w);
        ((u4v*)dst)[off] = p;
        return;
    }
    if (blockIdx.x >= 13312) {
        const int bi2 = blockIdx.x - 13312;
        if (bi2 < 64) {
            __shared__ float T[64][65];
            const int tr = bi2 >> 3, tc = bi2 & 7;
            const int rr0 = t >> 4, cc0 = (t & 15) * 4;
#pragma unroll
            for (int i2 = 0; i2 < 4; ++i2) {
                const int r = i2 * 16 + rr0;
                const float4 v = *(const float4*)&Wo[(size_t)(tr * 64 + r) * 512 + tc * 64 + cc0];
                T[r][cc0] = v.x; T[r][cc0 + 1] = v.y; T[r][cc0 + 2] = v.z; T[r][cc0 + 3] = v.w;
            }
            __syncthreads();
#pragma unroll
            for (int i2 = 0; i2 < 4; ++i2) {
                const int r2 = i2 * 16 + rr0;
                u4v p;
                p[0] = f2bf(T[cc0][r2]);     p[1] = f2bf(T[cc0 + 1][r2]);
                p[2] = f2bf(T[cc0 + 2][r2]); p[3] = f2bf(T[cc0 + 3][r2]);
                *(u4v*)&WoT[(size_t)(tc * 64 + r2) * 512 + tr * 64 + cc0] = p;
            }
        } else {
            // row 512 of WoT_ext = bo (feeds bias column of Wcomb)
            WoT[262144 + t]       = f2bf(bo_g[t]);
            WoT[262144 + 256 + t] = f2bf(bo_g[t + 256]);
        }
        return;
    }
    // ---- mem softmax (no max-subtraction needed: vals in [0, 1.78]) ----
    const int bi = blockIdx.x - 5120;
    const int i = bi & (kS - 1);
    const float* renr = ren + (size_t)bi * kS;
    const float* tsr  = ts  + (size_t)bi * kS;
    unsigned short* memr = mem + (size_t)bi * kS;
    const int j0 = t * 4;
    const float4 r4 = *(const float4*)(renr + j0);
    const float4 t4 = *(const float4*)(tsr + j0);
    float rv[4] = {r4.x, r4.y, r4.z, r4.w};
    float tv[4] = {t4.x, t4.y, t4.z, t4.w};
    float p4[4];
    float lsum = 0.0f;
#pragma unroll
    for (int e = 0; e < 4; ++e) {
        const int j = j0 + e;
        float p = 0.0f;
        if (j <= i) {
            const float val = 0.30102999566f * __log2f(rv[e] + 1.0f) + __expf(-fabsf(tv[e]));
            p = __expf(val);
        }
        p4[e] = p;
        lsum += p;
    }
#pragma unroll
    for (int d = 1; d < 64; d <<= 1) lsum += __shfl_xor(lsum, d);
    if ((t & 63) == 0) red[t >> 6] = lsum;
    __syncthreads();
    const float Z = red[0] + red[1] + red[2] + red[3];
    const float inv = 1.0f / Z;
    u4v pk;
#pragma unroll
    for (int e = 0; e < 4; ++e) pk[e] = f2bf(p4[e] * inv);
    *(u4v*)(memr + j0) = pk;
}

// ---------------- MFMA GEMM core: acc(128 x NT*32) = A @ B^T, K=512 ----------------
template <int NT>
__device__ __forceinline__ void mfma_core2(
    const unsigned short* __restrict__ A, const unsigned short* __restrict__ B,
    int M0, int N0, unsigned short* As, unsigned short* Bs, f4v (&acc)[4][NT])
{
    const int t = threadIdx.x, w = t >> 6, lane = t & 63;
    const int l16 = lane & 15, quad = lane >> 4;
    const int wm = (w & 1) * 64, wn = (w >> 1) * (NT * 16);
    constexpr int NB = NT / 2; // B-staging instrs per wave

    const unsigned short* gA[2]; unsigned short* lA[2];
#pragma unroll
    for (int i = 0; i < 2; ++i) {
        const int r0 = w * 32 + i * 16;
        const int r = r0 + (lane >> 2);
        const int c = (lane & 3) ^ ((r >> 1) & 3);
        gA[i] = A + (size_t)(M0 + r) * 512 + c * 8;
        lA[i] = As + r0 * 32;
    }
    const unsigned short* gB[NB]; unsigned short* lB[NB];
#pragma unroll
    for (int i = 0; i < NB; ++i) {
        const int r0 = w * (16 * NB) + i * 16;
        const int r = r0 + (lane >> 2);
        const int c = (lane & 3) ^ ((r >> 1) & 3);
        gB[i] = B + (size_t)(N0 + r) * 512 + c * 8;
        lB[i] = Bs + r0 * 32;
    }

    const f4v zero = {0.0f, 0.0f, 0.0f, 0.0f};
#pragma unroll
    for (int mt = 0; mt < 4; ++mt)
#pragma unroll
        for (int nt = 0; nt < NT; ++nt) acc[mt][nt] = zero;

#pragma unroll 1
    for (int k0 = 0; k0 < 512; k0 += 32) {
        gl2lds(gA[0] + k0, lA[0]);
        gl2lds(gA[1] + k0, lA[1]);
#pragma unroll
        for (int i = 0; i < NB; ++i) gl2lds(gB[i] + k0, lB[i]);
        __syncthreads();
        s8v af[4], bf_[NT];
#pragma unroll
        for (int mt = 0; mt < 4; ++mt) {
            const int r = wm + mt * 16 + l16;
            const int p = r * 4 + (quad ^ ((r >> 1) & 3));
            af[mt] = *(const s8v*)&As[p * 8];
        }
#pragma unroll
        for (int nt = 0; nt < NT; ++nt) {
            const int r = wn + nt * 16 + l16;
            const int p = r * 4 + (quad ^ ((r >> 1) & 3));
            bf_[nt] = *(const s8v*)&Bs[p * 8];
        }
#pragma unroll
        for (int mt = 0; mt < 4; ++mt)
#pragma unroll
            for (int nt = 0; nt < NT; ++nt)
                acc[mt][nt] = __builtin_amdgcn_mfma_f32_16x16x32_bf16(
                    af[mt], bf_[nt], acc[mt][nt], 0, 0, 0);
        __syncthreads();
    }
}

// ---- fused QKV (+ Wcomb build). y<8: acc = X @ [Wq;Wk]^T -> q/k (B,H,S,HD).
//      y in [8,12): SWAPPED acc = Wv @ X^T -> coalesced vT (B,H,HD,S) stores.
//      y == 12 (x<36): Wcomb = W1' @ Wo  (B = WoT, extra col 512 = bias)
__global__ __launch_bounds__(256) void qkv_mfma_kernel(
    const unsigned short* __restrict__ Xbf, const unsigned short* __restrict__ Wqkv,
    const float* __restrict__ bq, const float* __restrict__ bk, const float* __restrict__ bv,
    const unsigned short* __restrict__ W1bf, const unsigned short* __restrict__ WoT,
    const float* __restrict__ b1,
    unsigned short* __restrict__ qbf, unsigned short* __restrict__ kbf,
    unsigned short* __restrict__ vTbf,
    unsigned short* __restrict__ Wcomb, float* __restrict__ bcomb)
{
    __shared__ __align__(16) unsigned short As[128 * 32];
    __shared__ __align__(16) unsigned short Bs[128 * 32];
    const int y = blockIdx.y;
    const int t = threadIdx.x, w = t >> 6, lane = t & 63;
    const int l16 = lane & 15, quad = lane >> 4;

    if (y == 12) {
        if (blockIdx.x >= 36) return;
        f4v acc[4][2];
        const int M0 = (blockIdx.x / 9) * 128, N0 = (blockIdx.x % 9) * 64;
        mfma_core2<2>(W1bf, WoT, M0, N0, As, Bs, acc);
        const int wm = (w & 1) * 64, wn = (w >> 1) * 32;
#pragma unroll
        for (int nt = 0; nt < 2; ++nt) {
            const int qq = N0 + wn + nt * 16 + l16;
#pragma unroll
            for (int mt = 0; mt < 4; ++mt)
#pragma unroll
                for (int rr = 0; rr < 4; ++rr) {
                    const int m = M0 + wm + mt * 16 + quad * 4 + rr;
                    if (qq < 512)       Wcomb[(size_t)m * 512 + qq] = f2bf(acc[mt][nt][rr]);
                    else if (qq == 512) bcomb[m] = acc[mt][nt][rr] + b1[m];
                }
        }
        return;
    }

    f4v acc[4][4];
    const int wm = (w & 1) * 64, wn = (w >> 1) * 64;
    if (y < 8) {
        const int M0 = blockIdx.x * 128, N0 = y * 128;
        mfma_core2<4>(Xbf, Wqkv, M0, N0, As, Bs, acc);
        const int z = N0 >> 9; // 0:q 1:k
        const float* bias = (z == 0) ? bq : bk;
        unsigned short* out = (z == 0) ? qbf : kbf;
#pragma unroll
        for (int nt = 0; nt < 4; ++nt) {
            const int n512 = (N0 + wn + nt * 16 + l16) & 511;
            const int h = n512 >> 6, hd = n512 & 63;
            const float bv_ = bias[n512];
#pragma unroll
            for (int mt = 0; mt < 4; ++mt) {
#pragma unroll
                for (int rr = 0; rr < 4; ++rr) {
                    const int m = M0 + wm + mt * 16 + quad * 4 + rr;
                    const int b = m >> 10, s = m & (kS - 1);
                    out[(((size_t)b * kH + h) * kS + s) * kHD + hd] =
                        f2bf(acc[mt][nt][rr] + bv_);
                }
            }
        }
    } else {
        const int M0 = (y - 8) * 128, N0 = blockIdx.x * 128;
        mfma_core2<4>(Wqkv + (size_t)1024 * 512, Xbf, M0, N0, As, Bs, acc);
#pragma unroll
        for (int mt = 0; mt < 4; ++mt) {
#pragma unroll
            for (int rr = 0; rr < 4; ++rr) {
                const int vcol = M0 + wm + mt * 16 + quad * 4 + rr;
                const int h = vcol >> 6, hd = vcol & 63;
                const float bv_ = bv[vcol];
#pragma unroll
                for (int nt = 0; nt < 4; ++nt) {
                    const int sg = N0 + wn + nt * 16 + l16;
                    const int b = sg >> 10, s = sg & (kS - 1);
                    vTbf[(((size_t)b * kH + h) * kHD + hd) * kS + s] =
                        f2bf(acc[mt][nt][rr] + bv_);
                }
            }
        }
    }
}

// ---- final GEMM (Wo and W1' both folded into Wcomb): out = aout@Wcomb^T + bcomb (fp32)
__global__ __launch_bounds__(256) void gemm_final_kernel(
    const unsigned short* __restrict__ Abf, const unsigned short* __restrict__ Wcomb,
    const float* __restrict__ bcomb, float* __restrict__ out)
{
    __shared__ __align__(16) unsigned short As[128 * 32];
    __shared__ __align__(16) unsigned short Bs[64 * 32];
    f4v acc[4][2];
    const int M0 = blockIdx.x * 128, N0 = blockIdx.y * 64;
    mfma_core2<2>(Abf, Wcomb, M0, N0, As, Bs, acc);
    const int t = threadIdx.x, w = t >> 6, lane = t & 63;
    const int l16 = lane & 15, quad = lane >> 4;
    const int wm = (w & 1) * 64, wn = (w >> 1) * 32;
#pragma unroll
    for (int nt = 0; nt < 2; ++nt) {
        const int n = N0 + wn + nt * 16 + l16;
        const float bv_ = bcomb[n];
#pragma unroll
        for (int mt = 0; mt < 4; ++mt)
#pragma unroll
            for (int rr = 0; rr < 4; ++rr) {
                const int m = M0 + wm + mt * 16 + quad * 4 + rr;
                out[(size_t)m * kD + n] = acc[mt][nt][rr] + bv_;
            }
    }
}

// ---------------- flash attention: 8-wave parity split-k ----------------
// Block = 512 threads. Waves 0-3 (g=0) do even k-tiles, waves 4-7 (g=1) odd.
// Paired q-tiles (qp, 15-qp): 17 tile-computes split ~8.5/8.5 across parities.
// K/V staged ONCE per block into 4 rotating LDS buffers; partial Oa/Om/lr
// combined through LDS at epilogue. LDS = 65536 + 16384 = 81920 B exactly
// -> 2 blocks/CU; __launch_bounds__(512,4) forces VGPR<=128 -> 16 waves/CU.
#define LDSFRAG(tile, r, c) (*(const s8v*)&(tile)[(size_t)(r) * 64 + ((((c) ^ ((r) & 7))) << 3)])

__global__ __launch_bounds__(512, 4) void flash_attn_kernel(
    const unsigned short* __restrict__ q, const unsigned short* __restrict__ k,
    const unsigned short* __restrict__ vT, const unsigned short* __restrict__ mem,
    const float* __restrict__ l1, unsigned short* __restrict__ aout)
{
    const int qp = blockIdx.x;           // 0..7
    const int hi = 15 - qp, lo = qp;
    const int h = blockIdx.y, b = blockIdx.z;
    const int bh = b * kH + h;
    const int t = threadIdx.x;
    const int w = t >> 6, w4 = w & 3, g = w >> 2;
    const int lane = t & 63;
    const int quad = lane >> 4, l16 = lane & 15;
    const float lam = l1[0];

    __shared__ __align__(16) unsigned short KV[4][2][64 * 64];   // 65536 B (4 rotating K+V buffers)
    __shared__ __align__(16) unsigned short P_lds[8][16 * 64];   // 16384 B (XOR-swizzled, per-wave)

    const int tbase[2] = {hi * 64, lo * 64};
    s8v qa[2][2];
    const unsigned short* mbase[2];
#pragma unroll
    for (int ti = 0; ti < 2; ++ti) {
        const unsigned short* qrow = q + ((size_t)bh * kS + tbase[ti] + w4 * 16 + l16) * kHD;
        qa[ti][0] = *(const s8v*)(qrow + quad * 8);
        qa[ti][1] = *(const s8v*)(qrow + 32 + quad * 8);
        mbase[ti] = mem + ((size_t)b * kS + tbase[ti] + w4 * 16 + l16) * kS;
    }

    const unsigned short* kb = k + (size_t)bh * kS * kHD;
    const unsigned short* vb = vT + (size_t)bh * kHD * kS;

    // staging: 32 segments (2 tiles x 16) over 8 waves; wave group g stages tile parity g
    const unsigned short* gsrc[4];
    int gstep[4], loff[4];
#pragma unroll
    for (int u = 0; u < 4; ++u) {
        const int sp = w4 * 4 + u;                       // 0..15 within tile
        const int rloc = (sp & 7) * 8 + (lane >> 3);
        const int chunk = (lane & 7) ^ ((lane >> 3) & 7);
        if (sp < 8) { gsrc[u] = kb + (size_t)rloc * kHD + chunk * 8; gstep[u] = 64 * kHD; loff[u] = (sp & 7) * 512; }
        else        { gsrc[u] = vb + (size_t)rloc * kS  + chunk * 8; gstep[u] = 64;       loff[u] = 4096 + (sp & 7) * 512; }
    }
    unsigned short* KVf = &KV[0][0][0];

    // prologue: stage tiles 0 (waves 0-3) and 1 (waves 4-7)
#pragma unroll
    for (int u = 0; u < 4; ++u)
        gl2lds(gsrc[u] + (size_t)g * gstep[u], KVf + g * 8192 + loff[u]);

    const f4v zero = {0.0f, 0.0f, 0.0f, 0.0f};
    f4v Oa[2][4], Om[2][4];
    float lr[2][4];
#pragma unroll
    for (int ti = 0; ti < 2; ++ti)
#pragma unroll
        for (int nt = 0; nt < 4; ++nt) {
            Oa[ti][nt] = zero; Om[ti][nt] = zero; lr[ti][nt] = 0.0f;
        }

    const int nI = hi / 2 + 1;
    for (int it = 0; it < nI; ++it) {
        __syncthreads();                 // staged tiles (2it,2it+1) resident; prev reads done
        const int kt = 2 * it + g;       // this wave's k-tile
        const int Tn = 2 * it + 2 + g;   // tile to prefetch
        if (Tn <= hi) {
#pragma unroll
            for (int u = 0; u < 4; ++u)
                gl2lds(gsrc[u] + (size_t)Tn * gstep[u], KVf + (Tn & 3) * 8192 + loff[u]);
        }
        const bool a0 = (kt <= hi);
        const bool a1 = (kt <= lo);
        if (!a0) continue;               // barrier is at loop top: uniform across waves

        const int jn = kt * 64;
        s8v ma0a, ma0b, ma1a, ma1b;
        ma0a = *(const s8v*)(mbase[0] + jn + quad * 8);
        ma0b = *(const s8v*)(mbase[0] + jn + 32 + quad * 8);
        if (a1) {
            ma1a = *(const s8v*)(mbase[1] + jn + quad * 8);
            ma1b = *(const s8v*)(mbase[1] + jn + 32 + quad * 8);
        }
        const unsigned short* Kc = &KV[kt & 3][0][0];
        const unsigned short* Vc = &KV[kt & 3][1][0];

        s8v vf[4][2];
#pragma unroll
        for (int nt = 0; nt < 4; ++nt) {
            const int r = nt * 16 + l16;
            vf[nt][0] = LDSFRAG(Vc, r, quad);
            vf[nt][1] = LDSFRAG(Vc, r, 4 + quad);
        }

#pragma unroll
        for (int ti = 0; ti < 2; ++ti) {
            if (ti == 1 && !a1) continue;
            const bool diag = (kt == ((ti == 0) ? hi : lo));
#pragma unroll
            for (int ct = 0; ct < 4; ++ct) {
                const int r = ct * 16 + l16;
                const s8v kb0 = LDSFRAG(Kc, r, quad);
                const s8v kb1 = LDSFRAG(Kc, r, 4 + quad);
                f4v acc = zero;
                acc = __builtin_amdgcn_mfma_f32_16x16x32_bf16(qa[ti][0], kb0, acc, 0, 0, 0);
                acc = __builtin_amdgcn_mfma_f32_16x16x32_bf16(qa[ti][1], kb1, acc, 0, 0, 0);
#pragma unroll
                for (int rr = 0; rr < 4; ++rr) {
                    float p = __expf(acc[rr] * 0.125f);
                    if (diag && r > (w4 * 16 + quad * 4 + rr)) p = 0.0f;
                    lr[ti][rr] += p;
                    const int pr = quad * 4 + rr;
                    P_lds[w][pr * 64 + ((((ct * 2 + (l16 >> 3)) ^ (pr & 7)) << 3) | (l16 & 7))] = f2bf(p);
                }
            }
            const s8v pa0 = LDSFRAG(&P_lds[w][0], l16, quad);
            const s8v pa1 = LDSFRAG(&P_lds[w][0], l16, 4 + quad);
            const s8v m0 = (ti == 0) ? ma0a : ma1a;
            const s8v m1 = (ti == 0) ? ma0b : ma1b;
#pragma unroll
            for (int nt = 0; nt < 4; ++nt) {
                Oa[ti][nt] = __builtin_amdgcn_mfma_f32_16x16x32_bf16(pa0, vf[nt][0], Oa[ti][nt], 0, 0, 0);
                Oa[ti][nt] = __builtin_amdgcn_mfma_f32_16x16x32_bf16(pa1, vf[nt][1], Oa[ti][nt], 0, 0, 0);
                Om[ti][nt] = __builtin_amdgcn_mfma_f32_16x16x32_bf16(m0, vf[nt][0], Om[ti][nt], 0, 0, 0);
                Om[ti][nt] = __builtin_amdgcn_mfma_f32_16x16x32_bf16(m1, vf[nt][1], Om[ti][nt], 0, 0, 0);
            }
        }
    }

    // ---- combine parity partials via P_lds region (f32 view), then epilogue ----
    float* Pf = (float*)&P_lds[0][0];    // 4096 floats
    const int cbase = (w4 * 64 + lane) * 16;
#pragma unroll
    for (int ti = 0; ti < 2; ++ti) {
        __syncthreads();
        if (g) {
#pragma unroll
            for (int nt = 0; nt < 4; ++nt) *(f4v*)&Pf[cbase + nt * 4] = Oa[ti][nt];
        }
        __syncthreads();
        if (!g) {
#pragma unroll
            for (int nt = 0; nt < 4; ++nt) Oa[ti][nt] += *(const f4v*)&Pf[cbase + nt * 4];
        }
        __syncthreads();
        if (g) {
#pragma unroll
            for (int nt = 0; nt < 4; ++nt) *(f4v*)&Pf[cbase + nt * 4] = Om[ti][nt];
        }
        __syncthreads();
        if (!g) {
#pragma unroll
            for (int nt = 0; nt < 4; ++nt) Om[ti][nt] += *(const f4v*)&Pf[cbase + nt * 4];
        }
    }
    __syncthreads();
    if (g) {
        const int lbase = (w4 * 64 + lane) * 8;
#pragma unroll
        for (int ti = 0; ti < 2; ++ti)
#pragma unroll
            for (int rr = 0; rr < 4; ++rr) Pf[lbase + ti * 4 + rr] = lr[ti][rr];
    }
    __syncthreads();
    if (g) return;                        // no barriers below
    {
        const int lbase = (w4 * 64 + lane) * 8;
#pragma unroll
        for (int ti = 0; ti < 2; ++ti)
#pragma unroll
            for (int rr = 0; rr < 4; ++rr) lr[ti][rr] += Pf[lbase + ti * 4 + rr];
    }

    // normalize + blend, both tiles (waves 0-3 only)
#pragma unroll
    for (int ti = 0; ti < 2; ++ti) {
        float inv[4];
#pragma unroll
        for (int rr = 0; rr < 4; ++rr) {
            float Z = lr[ti][rr];
            Z += __shfl_xor(Z, 1);
            Z += __shfl_xor(Z, 2);
            Z += __shfl_xor(Z, 4);
            Z += __shfl_xor(Z, 8);
            inv[rr] = (1.0f - lam) / Z;
        }
        const int r0 = tbase[ti] + w4 * 16;
#pragma unroll
        for (int nt = 0; nt < 4; ++nt)
#pragma unroll
            for (int rr = 0; rr < 4; ++rr) {
                const int i = r0 + quad * 4 + rr;
                const int d = h * kHD + nt * 16 + l16;
                aout[((size_t)b * kS + i) * kD + d] =
                    f2bf(Oa[ti][nt][rr] * inv[rr] + lam * Om[ti][nt][rr]);
            }
    }
}

// ---------------- LayerNorm ----------------
__global__ __launch_bounds__(256) void ln_kernel(
    const float* __restrict__ x, const float* __restrict__ g,
    const float* __restrict__ bb, float* __restrict__ out)
{
    const int row = blockIdx.x;
    const int t = threadIdx.x;
    const float* xr = x + (size_t)row * kD;
    float a = xr[t], c = xr[t + 256];
    __shared__ float red[256];
    float s1 = a + c, s2 = a * a + c * c;
    red[t] = s1;
    __syncthreads();
    for (int s = 128; s > 0; s >>= 1) {
        if (t < s) red[t] += red[t + s];
        __syncthreads();
    }
    const float sum = red[0];
    __syncthreads();
    red[t] = s2;
    __syncthreads();
    for (int s = 128; s > 0; s >>= 1) {
        if (t < s) red[t] += red[t + s];
        __syncthreads();
    }
    const float sq = red[0];
    float mu = sum * (1.0f / kD);
    float var = sq * (1.0f / kD) - mu * mu;
    float inv = rsqrtf(var + 1e-5f);
    out[(size_t)row * kD + t]       = (a - mu) * inv * g[t] + bb[t];
    out[(size_t)row * kD + t + 256] = (c - mu) * inv * g[t + 256] + bb[t + 256];
}

extern "C" void kernel_launch(void* const* d_in, const int* in_sizes, int n_in,
                              void* d_out, int out_size, void* d_ws, size_t ws_size,
                              hipStream_t stream) {
    const float* X   = (const float*)d_in[1];   // 'inputs' feeds q,k,v (query unused)
    const float* ren = (const float*)d_in[2];
    const float* ts  = (const float*)d_in[3];
    const float* Wq = (const float*)d_in[5];  const float* bq = (const float*)d_in[6];
    const float* Wk = (const float*)d_in[7];  const float* bk = (const float*)d_in[8];
    const float* Wv = (const float*)d_in[9];  const float* bv = (const float*)d_in[10];
    const float* Wo = (const float*)d_in[11]; const float* bo = (const float*)d_in[12];
    const float* W1 = (const float*)d_in[13]; const float* b1 = (const float*)d_in[14];
    const float* lng = (const float*)d_in[15]; const float* lnb = (const float*)d_in[16];
    const float* l1 = (const float*)d_in[17];
    float* out = (float*)d_out;

    char* wsb = (char*)d_ws;
    unsigned short* Xbf    = (unsigned short*)(wsb);                  // 8 MB
    unsigned short* Wqkvbf = (unsigned short*)(wsb + (8u  << 20));    // 1.5 MB
    unsigned short* WoTbf  = (unsigned short*)(wsb + (10u << 20));    // 576x512 bf16 (0.57 MB)
    unsigned short* W1bf   = (unsigned short*)(wsb + (11u << 20));    // 0.5 MB
    unsigned short* qbf    = (unsigned short*)(wsb + (12u << 20));    // 8 MB
    unsigned short* kbf    = (unsigned short*)(wsb + (20u << 20));    // 8 MB
    unsigned short* vTbf   = (unsigned short*)(wsb + (28u << 20));    // 8 MB
    unsigned short* membf  = (unsigned short*)(wsb + (36u << 20));    // 16 MB
    unsigned short* aoutbf = (unsigned short*)(wsb + (52u << 20));    // 8 MB
    unsigned short* Wcombf = (unsigned short*)(wsb + (60u << 20));    // 0.5 MB
    float*          bcombf = (float*)        (wsb + (61u << 20));     // 2 KB

    prep_kernel<<<dim3(13377), 256, 0, stream>>>(
        X, Wq, Wk, Wv, Wo, W1, ren, ts, bo, Xbf, Wqkvbf, WoTbf, W1bf, membf);
    qkv_mfma_kernel<<<dim3(kM / 128, 13), 256, 0, stream>>>(
        Xbf, Wqkvbf, bq, bk, bv, W1bf, WoTbf, b1, qbf, kbf, vTbf, Wcombf, bcombf);
    flash_attn_kernel<<<dim3(8, kH, kB), 512, 0, stream>>>(
        qbf, kbf, vTbf, membf, l1, aoutbf);
    gemm_final_kernel<<<dim3(kM / 128, kD / 64), 256, 0, stream>>>(
        aoutbf, Wcombf, bcombf, out);
    ln_kernel<<<dim3(kM), 256, 0, stream>>>(out, lng, lnb, out);
}

// Round 5
// 263.088 us; speedup vs baseline: 1.4018x; 1.4018x over previous
//
#include <hip/hip_runtime.h>
#include <math.h>

constexpr int kB = 8, kS = 1024, kD = 512, kH = 8, kHD = 64;
constexpr int kM = kB * kS; // 8192 rows

typedef __attribute__((ext_vector_type(8))) short s8v;    // 8 bf16 (A/B frag)
typedef __attribute__((ext_vector_type(4))) float f4v;    // C/D frag
typedef __attribute__((ext_vector_type(4))) unsigned short u4v;

__device__ __forceinline__ unsigned short f2bf(float f) {
    union { float f; unsigned int u; } c; c.f = f;
    unsigned int u = c.u + 0x7FFFu + ((c.u >> 16) & 1u);
    return (unsigned short)(u >> 16);
}

// async global->LDS, 16B per lane; LDS dest = wave-uniform base + lane*16
__device__ __forceinline__ void gl2lds(const unsigned short* g, unsigned short* l) {
    __builtin_amdgcn_global_load_lds(
        (const __attribute__((address_space(1))) unsigned int*)g,
        (__attribute__((address_space(3))) unsigned int*)l, 16, 0, 0);
}

// ---------------- prep: fp32->bf16 cvt (+ I folded into W1), Wo^T transpose,
//                  bo row append, AND mem softmax ----------------
// blocks [0,5120): cvt float4 segments (X, Wq, Wk, Wv, W1')
// blocks [5120,13312): mem-softmax rows
// blocks [13312,13376): Wo transpose 64x64 tiles -> WoT (bf16)
// block 13376: WoT row 512 = bo (bias column for Wcomb GEMM)
__global__ __launch_bounds__(256) void prep_kernel(
    const float* __restrict__ X, const float* __restrict__ Wq,
    const float* __restrict__ Wk, const float* __restrict__ Wv,
    const float* __restrict__ Wo, const float* __restrict__ W1,
    const float* __restrict__ ren, const float* __restrict__ ts,
    const float* __restrict__ bo_g,
    unsigned short* __restrict__ Xbf, unsigned short* __restrict__ Wqkv,
    unsigned short* __restrict__ WoT, unsigned short* __restrict__ W1bf,
    unsigned short* __restrict__ mem)
{
    __shared__ float red[4];
    const int t = threadIdx.x;
    if (blockIdx.x < 5120) {
        const int idx = blockIdx.x * 256 + t;
        const float* src; unsigned short* dst; int off; bool isw1 = false;
        if (idx < 1048576)      { src = X;  dst = Xbf;           off = idx; }
        else if (idx < 1114112) { src = Wq; dst = Wqkv;          off = idx - 1048576; }
        else if (idx < 1179648) { src = Wk; dst = Wqkv + 262144; off = idx - 1114112; }
        else if (idx < 1245184) { src = Wv; dst = Wqkv + 524288; off = idx - 1179648; }
        else                    { src = W1; dst = W1bf;          off = idx - 1245184; isw1 = true; }
        float4 v = ((const float4*)src)[off];
        if (isw1) { // fold residual: W1' = I + W1
            const int e0 = off * 4;
            const int row = e0 >> 9, col0 = e0 & 511;
            if (row >= col0 && row < col0 + 4) ((float*)&v)[row - col0] += 1.0f;
        }
        u4v p;
        p[0] = f2bf(v.x); p[1] = f2bf(v.y); p[2] = f2bf(v.z); p[3] = f2bf(v.w);
        ((u4v*)dst)[off] = p;
        return;
    }
    if (blockIdx.x >= 13312) {
        const int bi2 = blockIdx.x - 13312;
        if (bi2 < 64) {
            __shared__ float T[64][65];
            const int tr = bi2 >> 3, tc = bi2 & 7;
            const int rr0 = t >> 4, cc0 = (t & 15) * 4;
#pragma unroll
            for (int i2 = 0; i2 < 4; ++i2) {
                const int r = i2 * 16 + rr0;
                const float4 v = *(const float4*)&Wo[(size_t)(tr * 64 + r) * 512 + tc * 64 + cc0];
                T[r][cc0] = v.x; T[r][cc0 + 1] = v.y; T[r][cc0 + 2] = v.z; T[r][cc0 + 3] = v.w;
            }
            __syncthreads();
#pragma unroll
            for (int i2 = 0; i2 < 4; ++i2) {
                const int r2 = i2 * 16 + rr0;
                u4v p;
                p[0] = f2bf(T[cc0][r2]);     p[1] = f2bf(T[cc0 + 1][r2]);
                p[2] = f2bf(T[cc0 + 2][r2]); p[3] = f2bf(T[cc0 + 3][r2]);
                *(u4v*)&WoT[(size_t)(tc * 64 + r2) * 512 + tr * 64 + cc0] = p;
            }
        } else {
            // row 512 of WoT_ext = bo (feeds bias column of Wcomb)
            WoT[262144 + t]       = f2bf(bo_g[t]);
            WoT[262144 + 256 + t] = f2bf(bo_g[t + 256]);
        }
        return;
    }
    // ---- mem softmax (no max-subtraction needed: vals in [0, 1.78]) ----
    const int bi = blockIdx.x - 5120;
    const int i = bi & (kS - 1);
    const float* renr = ren + (size_t)bi * kS;
    const float* tsr  = ts  + (size_t)bi * kS;
    unsigned short* memr = mem + (size_t)bi * kS;
    const int j0 = t * 4;
    const float4 r4 = *(const float4*)(renr + j0);
    const float4 t4 = *(const float4*)(tsr + j0);
    float rv[4] = {r4.x, r4.y, r4.z, r4.w};
    float tv[4] = {t4.x, t4.y, t4.z, t4.w};
    float p4[4];
    float lsum = 0.0f;
#pragma unroll
    for (int e = 0; e < 4; ++e) {
        const int j = j0 + e;
        float p = 0.0f;
        if (j <= i) {
            const float val = 0.30102999566f * __log2f(rv[e] + 1.0f) + __expf(-fabsf(tv[e]));
            p = __expf(val);
        }
        p4[e] = p;
        lsum += p;
    }
#pragma unroll
    for (int d = 1; d < 64; d <<= 1) lsum += __shfl_xor(lsum, d);
    if ((t & 63) == 0) red[t >> 6] = lsum;
    __syncthreads();
    const float Z = red[0] + red[1] + red[2] + red[3];
    const float inv = 1.0f / Z;
    u4v pk;
#pragma unroll
    for (int e = 0; e < 4; ++e) pk[e] = f2bf(p4[e] * inv);
    *(u4v*)(memr + j0) = pk;
}

// ---------------- MFMA GEMM core: acc(128 x NT*32) = A @ B^T, K=512 ----------------
template <int NT>
__device__ __forceinline__ void mfma_core2(
    const unsigned short* __restrict__ A, const unsigned short* __restrict__ B,
    int M0, int N0, unsigned short* As, unsigned short* Bs, f4v (&acc)[4][NT])
{
    const int t = threadIdx.x, w = t >> 6, lane = t & 63;
    const int l16 = lane & 15, quad = lane >> 4;
    const int wm = (w & 1) * 64, wn = (w >> 1) * (NT * 16);
    constexpr int NB = NT / 2; // B-staging instrs per wave

    const unsigned short* gA[2]; unsigned short* lA[2];
#pragma unroll
    for (int i = 0; i < 2; ++i) {
        const int r0 = w * 32 + i * 16;
        const int r = r0 + (lane >> 2);
        const int c = (lane & 3) ^ ((r >> 1) & 3);
        gA[i] = A + (size_t)(M0 + r) * 512 + c * 8;
        lA[i] = As + r0 * 32;
    }
    const unsigned short* gB[NB]; unsigned short* lB[NB];
#pragma unroll
    for (int i = 0; i < NB; ++i) {
        const int r0 = w * (16 * NB) + i * 16;
        const int r = r0 + (lane >> 2);
        const int c = (lane & 3) ^ ((r >> 1) & 3);
        gB[i] = B + (size_t)(N0 + r) * 512 + c * 8;
        lB[i] = Bs + r0 * 32;
    }

    const f4v zero = {0.0f, 0.0f, 0.0f, 0.0f};
#pragma unroll
    for (int mt = 0; mt < 4; ++mt)
#pragma unroll
        for (int nt = 0; nt < NT; ++nt) acc[mt][nt] = zero;

#pragma unroll 1
    for (int k0 = 0; k0 < 512; k0 += 32) {
        gl2lds(gA[0] + k0, lA[0]);
        gl2lds(gA[1] + k0, lA[1]);
#pragma unroll
        for (int i = 0; i < NB; ++i) gl2lds(gB[i] + k0, lB[i]);
        __syncthreads();
        s8v af[4], bf_[NT];
#pragma unroll
        for (int mt = 0; mt < 4; ++mt) {
            const int r = wm + mt * 16 + l16;
            const int p = r * 4 + (quad ^ ((r >> 1) & 3));
            af[mt] = *(const s8v*)&As[p * 8];
        }
#pragma unroll
        for (int nt = 0; nt < NT; ++nt) {
            const int r = wn + nt * 16 + l16;
            const int p = r * 4 + (quad ^ ((r >> 1) & 3));
            bf_[nt] = *(const s8v*)&Bs[p * 8];
        }
#pragma unroll
        for (int mt = 0; mt < 4; ++mt)
#pragma unroll
            for (int nt = 0; nt < NT; ++nt)
                acc[mt][nt] = __builtin_amdgcn_mfma_f32_16x16x32_bf16(
                    af[mt], bf_[nt], acc[mt][nt], 0, 0, 0);
        __syncthreads();
    }
}

// ---- fused QKV (+ Wcomb build). y<8: acc = X @ [Wq;Wk]^T -> q/k (B,H,S,HD).
//      y in [8,12): SWAPPED acc = Wv @ X^T -> coalesced vT (B,H,HD,S) stores.
//      y == 12 (x<36): Wcomb = W1' @ Wo  (B = WoT, extra col 512 = bias)
__global__ __launch_bounds__(256) void qkv_mfma_kernel(
    const unsigned short* __restrict__ Xbf, const unsigned short* __restrict__ Wqkv,
    const float* __restrict__ bq, const float* __restrict__ bk, const float* __restrict__ bv,
    const unsigned short* __restrict__ W1bf, const unsigned short* __restrict__ WoT,
    const float* __restrict__ b1,
    unsigned short* __restrict__ qbf, unsigned short* __restrict__ kbf,
    unsigned short* __restrict__ vTbf,
    unsigned short* __restrict__ Wcomb, float* __restrict__ bcomb)
{
    __shared__ __align__(16) unsigned short As[128 * 32];
    __shared__ __align__(16) unsigned short Bs[128 * 32];
    const int y = blockIdx.y;
    const int t = threadIdx.x, w = t >> 6, lane = t & 63;
    const int l16 = lane & 15, quad = lane >> 4;

    if (y == 12) {
        if (blockIdx.x >= 36) return;
        f4v acc[4][2];
        const int M0 = (blockIdx.x / 9) * 128, N0 = (blockIdx.x % 9) * 64;
        mfma_core2<2>(W1bf, WoT, M0, N0, As, Bs, acc);
        const int wm = (w & 1) * 64, wn = (w >> 1) * 32;
#pragma unroll
        for (int nt = 0; nt < 2; ++nt) {
            const int qq = N0 + wn + nt * 16 + l16;
#pragma unroll
            for (int mt = 0; mt < 4; ++mt)
#pragma unroll
                for (int rr = 0; rr < 4; ++rr) {
                    const int m = M0 + wm + mt * 16 + quad * 4 + rr;
                    if (qq < 512)       Wcomb[(size_t)m * 512 + qq] = f2bf(acc[mt][nt][rr]);
                    else if (qq == 512) bcomb[m] = acc[mt][nt][rr] + b1[m];
                }
        }
        return;
    }

    f4v acc[4][4];
    const int wm = (w & 1) * 64, wn = (w >> 1) * 64;
    if (y < 8) {
        const int M0 = blockIdx.x * 128, N0 = y * 128;
        mfma_core2<4>(Xbf, Wqkv, M0, N0, As, Bs, acc);
        const int z = N0 >> 9; // 0:q 1:k
        const float* bias = (z == 0) ? bq : bk;
        unsigned short* out = (z == 0) ? qbf : kbf;
#pragma unroll
        for (int nt = 0; nt < 4; ++nt) {
            const int n512 = (N0 + wn + nt * 16 + l16) & 511;
            const int h = n512 >> 6, hd = n512 & 63;
            const float bv_ = bias[n512];
#pragma unroll
            for (int mt = 0; mt < 4; ++mt) {
#pragma unroll
                for (int rr = 0; rr < 4; ++rr) {
                    const int m = M0 + wm + mt * 16 + quad * 4 + rr;
                    const int b = m >> 10, s = m & (kS - 1);
                    out[(((size_t)b * kH + h) * kS + s) * kHD + hd] =
                        f2bf(acc[mt][nt][rr] + bv_);
                }
            }
        }
    } else {
        const int M0 = (y - 8) * 128, N0 = blockIdx.x * 128;
        mfma_core2<4>(Wqkv + (size_t)1024 * 512, Xbf, M0, N0, As, Bs, acc);
#pragma unroll
        for (int mt = 0; mt < 4; ++mt) {
#pragma unroll
            for (int rr = 0; rr < 4; ++rr) {
                const int vcol = M0 + wm + mt * 16 + quad * 4 + rr;
                const int h = vcol >> 6, hd = vcol & 63;
                const float bv_ = bv[vcol];
#pragma unroll
                for (int nt = 0; nt < 4; ++nt) {
                    const int sg = N0 + wn + nt * 16 + l16;
                    const int b = sg >> 10, s = sg & (kS - 1);
                    vTbf[(((size_t)b * kH + h) * kHD + hd) * kS + s] =
                        f2bf(acc[mt][nt][rr] + bv_);
                }
            }
        }
    }
}

// ---- final GEMM (Wo and W1' both folded into Wcomb): out = aout@Wcomb^T + bcomb (fp32)
__global__ __launch_bounds__(256) void gemm_final_kernel(
    const unsigned short* __restrict__ Abf, const unsigned short* __restrict__ Wcomb,
    const float* __restrict__ bcomb, float* __restrict__ out)
{
    __shared__ __align__(16) unsigned short As[128 * 32];
    __shared__ __align__(16) unsigned short Bs[64 * 32];
    f4v acc[4][2];
    const int M0 = blockIdx.x * 128, N0 = blockIdx.y * 64;
    mfma_core2<2>(Abf, Wcomb, M0, N0, As, Bs, acc);
    const int t = threadIdx.x, w = t >> 6, lane = t & 63;
    const int l16 = lane & 15, quad = lane >> 4;
    const int wm = (w & 1) * 64, wn = (w >> 1) * 32;
#pragma unroll
    for (int nt = 0; nt < 2; ++nt) {
        const int n = N0 + wn + nt * 16 + l16;
        const float bv_ = bcomb[n];
#pragma unroll
        for (int mt = 0; mt < 4; ++mt)
#pragma unroll
            for (int rr = 0; rr < 4; ++rr) {
                const int m = M0 + wm + mt * 16 + quad * 4 + rr;
                out[(size_t)m * kD + n] = acc[mt][nt][rr] + bv_;
            }
    }
}

// ---------------- flash attention: one 64-row q-tile per block ----------------
// Grid 16 x H x B = 1024 blocks (4/CU), 256 threads. qt = 15 - blockIdx.x so the
// 16-k-tile blocks dispatch first (causal imbalance smoothed by launch order).
// LDS = KV dbuf 32 KB + swizzled P_lds 8 KB = 40960 B -> 4 blocks/CU exactly.
// Single q-tile halves accumulator state vs paired version -> fits 128 VGPR.
#define LDSFRAG(tile, r, c) (*(const s8v*)&(tile)[(size_t)(r) * 64 + ((((c) ^ ((r) & 7))) << 3)])

__global__ __launch_bounds__(256, 4) void flash_attn_kernel(
    const unsigned short* __restrict__ q, const unsigned short* __restrict__ k,
    const unsigned short* __restrict__ vT, const unsigned short* __restrict__ mem,
    const float* __restrict__ l1, unsigned short* __restrict__ aout)
{
    const int qt = 15 - blockIdx.x;      // largest-work blocks first
    const int h = blockIdx.y, b = blockIdx.z;
    const int bh = b * kH + h;
    const int t = threadIdx.x;
    const int w = t >> 6, lane = t & 63;
    const int quad = lane >> 4, l16 = lane & 15;
    const float lam = l1[0];

    __shared__ __align__(16) unsigned short KV[2][2][64 * 64];   // 32 KB (dbuf K+V)
    __shared__ __align__(16) unsigned short P_lds[4][16 * 64];   // 8 KB (XOR-swizzled, per-wave)

    const int qbase = qt * 64;
    const unsigned short* qrow = q + ((size_t)bh * kS + qbase + w * 16 + l16) * kHD;
    const s8v qa0 = *(const s8v*)(qrow + quad * 8);
    const s8v qa1 = *(const s8v*)(qrow + 32 + quad * 8);
    const unsigned short* mbase = mem + ((size_t)b * kS + qbase + w * 16 + l16) * kS;

    const unsigned short* kb = k + (size_t)bh * kS * kHD;
    const unsigned short* vb = vT + (size_t)bh * kHD * kS;

    // staging: 16 segments (8 K + 8 V) over 4 waves, 4 gl2lds per wave
    const unsigned short* gsrc[4];
    int gstep[4];
    unsigned short* ldst[4];
#pragma unroll
    for (int u = 0; u < 4; ++u) {
        const int sp = w * 4 + u;
        const int rloc = (sp & 7) * 8 + (lane >> 3);
        const int chunk = (lane & 7) ^ ((lane >> 3) & 7);
        if (sp < 8) { gsrc[u] = kb + (size_t)rloc * kHD + chunk * 8; gstep[u] = kHD; ldst[u] = &KV[0][0][(sp & 7) * 512]; }
        else        { gsrc[u] = vb + (size_t)rloc * kS  + chunk * 8; gstep[u] = 1;   ldst[u] = &KV[0][1][(sp & 7) * 512]; }
    }

    // prologue: stage k-tile 0
#pragma unroll
    for (int u = 0; u < 4; ++u) gl2lds(gsrc[u], ldst[u]);

    const f4v zero = {0.0f, 0.0f, 0.0f, 0.0f};
    f4v Oa[4], Om[4];
    float lr[4];
#pragma unroll
    for (int nt = 0; nt < 4; ++nt) { Oa[nt] = zero; Om[nt] = zero; lr[nt] = 0.0f; }

    for (int kt = 0; kt <= qt; ++kt) {
        __syncthreads();                 // stage(kt) landed; all waves done with other buf
        const int cur = kt & 1;
        if (kt < qt) {
            const int jn = (kt + 1) * 64;
            const int boff = ((kt + 1) & 1) * 8192;
#pragma unroll
            for (int u = 0; u < 4; ++u)
                gl2lds(gsrc[u] + (size_t)jn * gstep[u], ldst[u] + boff);
        }
        const int jm = kt * 64;
        const s8v ma0 = *(const s8v*)(mbase + jm + quad * 8);
        const s8v ma1 = *(const s8v*)(mbase + jm + 32 + quad * 8);
        const unsigned short* Kc = &KV[cur][0][0];
        const unsigned short* Vc = &KV[cur][1][0];
        const bool diag = (kt == qt);

        // QK^T -> p = exp(s/8) (masked -> 0); accumulate row sums in-lane
#pragma unroll
        for (int ct = 0; ct < 4; ++ct) {
            const int r = ct * 16 + l16;
            const s8v kb0 = LDSFRAG(Kc, r, quad);
            const s8v kb1 = LDSFRAG(Kc, r, 4 + quad);
            f4v acc = zero;
            acc = __builtin_amdgcn_mfma_f32_16x16x32_bf16(qa0, kb0, acc, 0, 0, 0);
            acc = __builtin_amdgcn_mfma_f32_16x16x32_bf16(qa1, kb1, acc, 0, 0, 0);
#pragma unroll
            for (int rr = 0; rr < 4; ++rr) {
                float p = __expf(acc[rr] * 0.125f);
                if (diag && r > (w * 16 + quad * 4 + rr)) p = 0.0f;
                lr[rr] += p;
                const int pr = quad * 4 + rr;
                P_lds[w][pr * 64 + ((((ct * 2 + (l16 >> 3)) ^ (pr & 7)) << 3) | (l16 & 7))] = f2bf(p);
            }
        }
        const s8v pa0 = LDSFRAG(&P_lds[w][0], l16, quad);
        const s8v pa1 = LDSFRAG(&P_lds[w][0], l16, 4 + quad);
#pragma unroll
        for (int nt = 0; nt < 4; ++nt) {
            const int r = nt * 16 + l16;
            const s8v vf0 = LDSFRAG(Vc, r, quad);
            const s8v vf1 = LDSFRAG(Vc, r, 4 + quad);
            Oa[nt] = __builtin_amdgcn_mfma_f32_16x16x32_bf16(pa0, vf0, Oa[nt], 0, 0, 0);
            Oa[nt] = __builtin_amdgcn_mfma_f32_16x16x32_bf16(pa1, vf1, Oa[nt], 0, 0, 0);
            Om[nt] = __builtin_amdgcn_mfma_f32_16x16x32_bf16(ma0, vf0, Om[nt], 0, 0, 0);
            Om[nt] = __builtin_amdgcn_mfma_f32_16x16x32_bf16(ma1, vf1, Om[nt], 0, 0, 0);
        }
    }

    // epilogue: normalize + blend
    float inv4[4];
#pragma unroll
    for (int rr = 0; rr < 4; ++rr) {
        float Z = lr[rr];
        Z += __shfl_xor(Z, 1);
        Z += __shfl_xor(Z, 2);
        Z += __shfl_xor(Z, 4);
        Z += __shfl_xor(Z, 8);
        inv4[rr] = (1.0f - lam) / Z;
    }
    const int r0 = qbase + w * 16;
#pragma unroll
    for (int nt = 0; nt < 4; ++nt)
#pragma unroll
        for (int rr = 0; rr < 4; ++rr) {
            const int i = r0 + quad * 4 + rr;
            const int d = h * kHD + nt * 16 + l16;
            aout[((size_t)b * kS + i) * kD + d] =
                f2bf(Oa[nt][rr] * inv4[rr] + lam * Om[nt][rr]);
        }
}

// ---------------- LayerNorm ----------------
__global__ __launch_bounds__(256) void ln_kernel(
    const float* __restrict__ x, const float* __restrict__ g,
    const float* __restrict__ bb, float* __restrict__ out)
{
    const int row = blockIdx.x;
    const int t = threadIdx.x;
    const float* xr = x + (size_t)row * kD;
    float a = xr[t], c = xr[t + 256];
    __shared__ float red[256];
    float s1 = a + c, s2 = a * a + c * c;
    red[t] = s1;
    __syncthreads();
    for (int s = 128; s > 0; s >>= 1) {
        if (t < s) red[t] += red[t + s];
        __syncthreads();
    }
    const float sum = red[0];
    __syncthreads();
    red[t] = s2;
    __syncthreads();
    for (int s = 128; s > 0; s >>= 1) {
        if (t < s) red[t] += red[t + s];
        __syncthreads();
    }
    const float sq = red[0];
    float mu = sum * (1.0f / kD);
    float var = sq * (1.0f / kD) - mu * mu;
    float inv = rsqrtf(var + 1e-5f);
    out[(size_t)row * kD + t]       = (a - mu) * inv * g[t] + bb[t];
    out[(size_t)row * kD + t + 256] = (c - mu) * inv * g[t + 256] + bb[t + 256];
}

extern "C" void kernel_launch(void* const* d_in, const int* in_sizes, int n_in,
                              void* d_out, int out_size, void* d_ws, size_t ws_size,
                              hipStream_t stream) {
    const float* X   = (const float*)d_in[1];   // 'inputs' feeds q,k,v (query unused)
    const float* ren = (const float*)d_in[2];
    const float* ts  = (const float*)d_in[3];
    const float* Wq = (const float*)d_in[5];  const float* bq = (const float*)d_in[6];
    const float* Wk = (const float*)d_in[7];  const float* bk = (const float*)d_in[8];
    const float* Wv = (const float*)d_in[9];  const float* bv = (const float*)d_in[10];
    const float* Wo = (const float*)d_in[11]; const float* bo = (const float*)d_in[12];
    const float* W1 = (const float*)d_in[13]; const float* b1 = (const float*)d_in[14];
    const float* lng = (const float*)d_in[15]; const float* lnb = (const float*)d_in[16];
    const float* l1 = (const float*)d_in[17];
    float* out = (float*)d_out;

    char* wsb = (char*)d_ws;
    unsigned short* Xbf    = (unsigned short*)(wsb);                  // 8 MB
    unsigned short* Wqkvbf = (unsigned short*)(wsb + (8u  << 20));    // 1.5 MB
    unsigned short* WoTbf  = (unsigned short*)(wsb + (10u << 20));    // 576x512 bf16 (0.57 MB)
    unsigned short* W1bf   = (unsigned short*)(wsb + (11u << 20));    // 0.5 MB
    unsigned short* qbf    = (unsigned short*)(wsb + (12u << 20));    // 8 MB
    unsigned short* kbf    = (unsigned short*)(wsb + (20u << 20));    // 8 MB
    unsigned short* vTbf   = (unsigned short*)(wsb + (28u << 20));    // 8 MB
    unsigned short* membf  = (unsigned short*)(wsb + (36u << 20));    // 16 MB
    unsigned short* aoutbf = (unsigned short*)(wsb + (52u << 20));    // 8 MB
    unsigned short* Wcombf = (unsigned short*)(wsb + (60u << 20));    // 0.5 MB
    float*          bcombf = (float*)        (wsb + (61u << 20));     // 2 KB

    prep_kernel<<<dim3(13377), 256, 0, stream>>>(
        X, Wq, Wk, Wv, Wo, W1, ren, ts, bo, Xbf, Wqkvbf, WoTbf, W1bf, membf);
    qkv_mfma_kernel<<<dim3(kM / 128, 13), 256, 0, stream>>>(
        Xbf, Wqkvbf, bq, bk, bv, W1bf, WoTbf, b1, qbf, kbf, vTbf, Wcombf, bcombf);
    flash_attn_kernel<<<dim3(16, kH, kB), 256, 0, stream>>>(
        qbf, kbf, vTbf, membf, l1, aoutbf);
    gemm_final_kernel<<<dim3(kM / 128, kD / 64), 256, 0, stream>>>(
        aoutbf, Wcombf, bcombf, out);
    ln_kernel<<<dim3(kM), 256, 0, stream>>>(out, lng, lnb, out);
}

// Round 6
// 249.082 us; speedup vs baseline: 1.4807x; 1.0562x over previous
//
#include <hip/hip_runtime.h>
#include <math.h>

constexpr int kB = 8, kS = 1024, kD = 512, kH = 8, kHD = 64;
constexpr int kM = kB * kS; // 8192 rows

typedef __attribute__((ext_vector_type(8))) short s8v;    // 8 bf16 (A/B frag)
typedef __attribute__((ext_vector_type(4))) float f4v;    // C/D frag
typedef __attribute__((ext_vector_type(4))) unsigned short u4v;

__device__ __forceinline__ unsigned short f2bf(float f) {
    union { float f; unsigned int u; } c; c.f = f;
    unsigned int u = c.u + 0x7FFFu + ((c.u >> 16) & 1u);
    return (unsigned short)(u >> 16);
}

// async global->LDS, 16B per lane; LDS dest = wave-uniform base + lane*16
__device__ __forceinline__ void gl2lds(const unsigned short* g, unsigned short* l) {
    __builtin_amdgcn_global_load_lds(
        (const __attribute__((address_space(1))) unsigned int*)g,
        (__attribute__((address_space(3))) unsigned int*)l, 16, 0, 0);
}

// ---------------- prep: fp32->bf16 cvt (+ I folded into W1), Wo^T transpose,
//                  bo row append, AND mem softmax ----------------
__global__ __launch_bounds__(256) void prep_kernel(
    const float* __restrict__ X, const float* __restrict__ Wq,
    const float* __restrict__ Wk, const float* __restrict__ Wv,
    const float* __restrict__ Wo, const float* __restrict__ W1,
    const float* __restrict__ ren, const float* __restrict__ ts,
    const float* __restrict__ bo_g,
    unsigned short* __restrict__ Xbf, unsigned short* __restrict__ Wqkv,
    unsigned short* __restrict__ WoT, unsigned short* __restrict__ W1bf,
    unsigned short* __restrict__ mem)
{
    __shared__ float red[4];
    const int t = threadIdx.x;
    if (blockIdx.x < 5120) {
        const int idx = blockIdx.x * 256 + t;
        const float* src; unsigned short* dst; int off; bool isw1 = false;
        if (idx < 1048576)      { src = X;  dst = Xbf;           off = idx; }
        else if (idx < 1114112) { src = Wq; dst = Wqkv;          off = idx - 1048576; }
        else if (idx < 1179648) { src = Wk; dst = Wqkv + 262144; off = idx - 1114112; }
        else if (idx < 1245184) { src = Wv; dst = Wqkv + 524288; off = idx - 1179648; }
        else                    { src = W1; dst = W1bf;          off = idx - 1245184; isw1 = true; }
        float4 v = ((const float4*)src)[off];
        if (isw1) { // fold residual: W1' = I + W1
            const int e0 = off * 4;
            const int row = e0 >> 9, col0 = e0 & 511;
            if (row >= col0 && row < col0 + 4) ((float*)&v)[row - col0] += 1.0f;
        }
        u4v p;
        p[0] = f2bf(v.x); p[1] = f2bf(v.y); p[2] = f2bf(v.z); p[3] = f2bf(v.w);
        ((u4v*)dst)[off] = p;
        return;
    }
    if (blockIdx.x >= 13312) {
        const int bi2 = blockIdx.x - 13312;
        if (bi2 < 64) {
            __shared__ float T[64][65];
            const int tr = bi2 >> 3, tc = bi2 & 7;
            const int rr0 = t >> 4, cc0 = (t & 15) * 4;
#pragma unroll
            for (int i2 = 0; i2 < 4; ++i2) {
                const int r = i2 * 16 + rr0;
                const float4 v = *(const float4*)&Wo[(size_t)(tr * 64 + r) * 512 + tc * 64 + cc0];
                T[r][cc0] = v.x; T[r][cc0 + 1] = v.y; T[r][cc0 + 2] = v.z; T[r][cc0 + 3] = v.w;
            }
            __syncthreads();
#pragma unroll
            for (int i2 = 0; i2 < 4; ++i2) {
                const int r2 = i2 * 16 + rr0;
                u4v p;
                p[0] = f2bf(T[cc0][r2]);     p[1] = f2bf(T[cc0 + 1][r2]);
                p[2] = f2bf(T[cc0 + 2][r2]); p[3] = f2bf(T[cc0 + 3][r2]);
                *(u4v*)&WoT[(size_t)(tc * 64 + r2) * 512 + tr * 64 + cc0] = p;
            }
        } else {
            // row 512 of WoT_ext = bo (feeds bias column of Wcomb)
            WoT[262144 + t]       = f2bf(bo_g[t]);
            WoT[262144 + 256 + t] = f2bf(bo_g[t + 256]);
        }
        return;
    }
    // ---- mem softmax (no max-subtraction needed: vals in [0, 1.78]) ----
    const int bi = blockIdx.x - 5120;
    const int i = bi & (kS - 1);
    const float* renr = ren + (size_t)bi * kS;
    const float* tsr  = ts  + (size_t)bi * kS;
    unsigned short* memr = mem + (size_t)bi * kS;
    const int j0 = t * 4;
    const float4 r4 = *(const float4*)(renr + j0);
    const float4 t4 = *(const float4*)(tsr + j0);
    float rv[4] = {r4.x, r4.y, r4.z, r4.w};
    float tv[4] = {t4.x, t4.y, t4.z, t4.w};
    float p4[4];
    float lsum = 0.0f;
#pragma unroll
    for (int e = 0; e < 4; ++e) {
        const int j = j0 + e;
        float p = 0.0f;
        if (j <= i) {
            const float val = 0.30102999566f * __log2f(rv[e] + 1.0f) + __expf(-fabsf(tv[e]));
            p = __expf(val);
        }
        p4[e] = p;
        lsum += p;
    }
#pragma unroll
    for (int d = 1; d < 64; d <<= 1) lsum += __shfl_xor(lsum, d);
    if ((t & 63) == 0) red[t >> 6] = lsum;
    __syncthreads();
    const float Z = red[0] + red[1] + red[2] + red[3];
    const float inv = 1.0f / Z;
    u4v pk;
#pragma unroll
    for (int e = 0; e < 4; ++e) pk[e] = f2bf(p4[e] * inv);
    *(u4v*)(memr + j0) = pk;
}

// ------- MFMA GEMM core: acc(128 x NT*32) = A @ B^T, K=512 -------
// Double-buffered LDS, ONE barrier per K-step: prefetch(k+1) issued before
// compute(k); barrier at loop top drains the in-flight stage (vmcnt0) and
// protects buffer reuse. As: 2*4096 shorts. Bs: 2*(NT*1024) shorts.
template <int NT>
__device__ __forceinline__ void mfma_core2(
    const unsigned short* __restrict__ A, const unsigned short* __restrict__ B,
    int M0, int N0, unsigned short* As, unsigned short* Bs, f4v (&acc)[4][NT])
{
    const int t = threadIdx.x, w = t >> 6, lane = t & 63;
    const int l16 = lane & 15, quad = lane >> 4;
    const int wm = (w & 1) * 64, wn = (w >> 1) * (NT * 16);
    constexpr int NB = NT / 2;             // B-staging instrs per wave
    constexpr int ABUF = 128 * 32;         // shorts per A buffer
    constexpr int BBUF = NT * 32 * 32;     // shorts per B buffer (rows = 32*NT)

    const unsigned short* gA[2]; unsigned short* lA[2];
#pragma unroll
    for (int i = 0; i < 2; ++i) {
        const int r0 = w * 32 + i * 16;
        const int r = r0 + (lane >> 2);
        const int c = (lane & 3) ^ ((r >> 1) & 3);
        gA[i] = A + (size_t)(M0 + r) * 512 + c * 8;
        lA[i] = As + r0 * 32;
    }
    const unsigned short* gB[NB]; unsigned short* lB[NB];
#pragma unroll
    for (int i = 0; i < NB; ++i) {
        const int r0 = w * (16 * NB) + i * 16;
        const int r = r0 + (lane >> 2);
        const int c = (lane & 3) ^ ((r >> 1) & 3);
        gB[i] = B + (size_t)(N0 + r) * 512 + c * 8;
        lB[i] = Bs + r0 * 32;
    }

    const f4v zero = {0.0f, 0.0f, 0.0f, 0.0f};
#pragma unroll
    for (int mt = 0; mt < 4; ++mt)
#pragma unroll
        for (int nt = 0; nt < NT; ++nt) acc[mt][nt] = zero;

    // prologue: stage k0=0 into buffer 0
    gl2lds(gA[0], lA[0]);
    gl2lds(gA[1], lA[1]);
#pragma unroll
    for (int i = 0; i < NB; ++i) gl2lds(gB[i], lB[i]);

#pragma unroll 1
    for (int k0 = 0; k0 < 512; k0 += 32) {
        const int cur = (k0 >> 5) & 1;
        __syncthreads();                   // buf[cur] staged; prev reads done
        if (k0 + 32 < 512) {
            const int nb = cur ^ 1;
            gl2lds(gA[0] + k0 + 32, lA[0] + nb * ABUF);
            gl2lds(gA[1] + k0 + 32, lA[1] + nb * ABUF);
#pragma unroll
            for (int i = 0; i < NB; ++i) gl2lds(gB[i] + k0 + 32, lB[i] + nb * BBUF);
        }
        s8v af[4], bf_[NT];
#pragma unroll
        for (int mt = 0; mt < 4; ++mt) {
            const int r = wm + mt * 16 + l16;
            const int p = r * 4 + (quad ^ ((r >> 1) & 3));
            af[mt] = *(const s8v*)&As[cur * ABUF + p * 8];
        }
#pragma unroll
        for (int nt = 0; nt < NT; ++nt) {
            const int r = wn + nt * 16 + l16;
            const int p = r * 4 + (quad ^ ((r >> 1) & 3));
            bf_[nt] = *(const s8v*)&Bs[cur * BBUF + p * 8];
        }
#pragma unroll
        for (int mt = 0; mt < 4; ++mt)
#pragma unroll
            for (int nt = 0; nt < NT; ++nt)
                acc[mt][nt] = __builtin_amdgcn_mfma_f32_16x16x32_bf16(
                    af[mt], bf_[nt], acc[mt][nt], 0, 0, 0);
    }
}

// ---- fused QKV (+ Wcomb build). y<8: acc = X @ [Wq;Wk]^T -> q/k (B,H,S,HD).
//      y in [8,12): SWAPPED acc = Wv @ X^T -> coalesced vT (B,H,HD,S) stores.
//      y == 12 (x<36): Wcomb = W1' @ Wo  (B = WoT, extra col 512 = bias)
__global__ __launch_bounds__(256) void qkv_mfma_kernel(
    const unsigned short* __restrict__ Xbf, const unsigned short* __restrict__ Wqkv,
    const float* __restrict__ bq, const float* __restrict__ bk, const float* __restrict__ bv,
    const unsigned short* __restrict__ W1bf, const unsigned short* __restrict__ WoT,
    const float* __restrict__ b1,
    unsigned short* __restrict__ qbf, unsigned short* __restrict__ kbf,
    unsigned short* __restrict__ vTbf,
    unsigned short* __restrict__ Wcomb, float* __restrict__ bcomb)
{
    __shared__ __align__(16) unsigned short As[2 * 128 * 32];
    __shared__ __align__(16) unsigned short Bs[2 * 128 * 32];
    const int y = blockIdx.y;
    const int t = threadIdx.x, w = t >> 6, lane = t & 63;
    const int l16 = lane & 15, quad = lane >> 4;

    if (y == 12) {
        if (blockIdx.x >= 36) return;
        f4v acc[4][2];
        const int M0 = (blockIdx.x / 9) * 128, N0 = (blockIdx.x % 9) * 64;
        mfma_core2<2>(W1bf, WoT, M0, N0, As, Bs, acc);
        const int wm = (w & 1) * 64, wn = (w >> 1) * 32;
#pragma unroll
        for (int nt = 0; nt < 2; ++nt) {
            const int qq = N0 + wn + nt * 16 + l16;
#pragma unroll
            for (int mt = 0; mt < 4; ++mt)
#pragma unroll
                for (int rr = 0; rr < 4; ++rr) {
                    const int m = M0 + wm + mt * 16 + quad * 4 + rr;
                    if (qq < 512)       Wcomb[(size_t)m * 512 + qq] = f2bf(acc[mt][nt][rr]);
                    else if (qq == 512) bcomb[m] = acc[mt][nt][rr] + b1[m];
                }
        }
        return;
    }

    f4v acc[4][4];
    const int wm = (w & 1) * 64, wn = (w >> 1) * 64;
    if (y < 8) {
        const int M0 = blockIdx.x * 128, N0 = y * 128;
        mfma_core2<4>(Xbf, Wqkv, M0, N0, As, Bs, acc);
        const int z = N0 >> 9; // 0:q 1:k
        const float* bias = (z == 0) ? bq : bk;
        unsigned short* out = (z == 0) ? qbf : kbf;
#pragma unroll
        for (int nt = 0; nt < 4; ++nt) {
            const int n512 = (N0 + wn + nt * 16 + l16) & 511;
            const int h = n512 >> 6, hd = n512 & 63;
            const float bv_ = bias[n512];
#pragma unroll
            for (int mt = 0; mt < 4; ++mt) {
#pragma unroll
                for (int rr = 0; rr < 4; ++rr) {
                    const int m = M0 + wm + mt * 16 + quad * 4 + rr;
                    const int b = m >> 10, s = m & (kS - 1);
                    out[(((size_t)b * kH + h) * kS + s) * kHD + hd] =
                        f2bf(acc[mt][nt][rr] + bv_);
                }
            }
        }
    } else {
        const int M0 = (y - 8) * 128, N0 = blockIdx.x * 128;
        mfma_core2<4>(Wqkv + (size_t)1024 * 512, Xbf, M0, N0, As, Bs, acc);
#pragma unroll
        for (int mt = 0; mt < 4; ++mt) {
#pragma unroll
            for (int rr = 0; rr < 4; ++rr) {
                const int vcol = M0 + wm + mt * 16 + quad * 4 + rr;
                const int h = vcol >> 6, hd = vcol & 63;
                const float bv_ = bv[vcol];
#pragma unroll
                for (int nt = 0; nt < 4; ++nt) {
                    const int sg = N0 + wn + nt * 16 + l16;
                    const int b = sg >> 10, s = sg & (kS - 1);
                    vTbf[(((size_t)b * kH + h) * kHD + hd) * kS + s] =
                        f2bf(acc[mt][nt][rr] + bv_);
                }
            }
        }
    }
}

// ---- final GEMM (Wo and W1' both folded into Wcomb): out = aout@Wcomb^T + bcomb (fp32)
__global__ __launch_bounds__(256) void gemm_final_kernel(
    const unsigned short* __restrict__ Abf, const unsigned short* __restrict__ Wcomb,
    const float* __restrict__ bcomb, float* __restrict__ out)
{
    __shared__ __align__(16) unsigned short As[2 * 128 * 32];
    __shared__ __align__(16) unsigned short Bs[2 * 64 * 32];
    f4v acc[4][2];
    const int M0 = blockIdx.x * 128, N0 = blockIdx.y * 64;
    mfma_core2<2>(Abf, Wcomb, M0, N0, As, Bs, acc);
    const int t = threadIdx.x, w = t >> 6, lane = t & 63;
    const int l16 = lane & 15, quad = lane >> 4;
    const int wm = (w & 1) * 64, wn = (w >> 1) * 32;
#pragma unroll
    for (int nt = 0; nt < 2; ++nt) {
        const int n = N0 + wn + nt * 16 + l16;
        const float bv_ = bcomb[n];
#pragma unroll
        for (int mt = 0; mt < 4; ++mt)
#pragma unroll
            for (int rr = 0; rr < 4; ++rr) {
                const int m = M0 + wm + mt * 16 + quad * 4 + rr;
                out[(size_t)m * kD + n] = acc[mt][nt][rr] + bv_;
            }
    }
}

// ---------------- flash attention: KVBLK=128, one 64-row q-tile per block ----
// Empirical law (r0 vs r5): duration = max_iterations x ~3.1us, independent of
// per-iteration work. So halve iterations: K-tile 128x64, V-tile 64x128, dbuf.
// nkt = qt/2+1 (max 8). LDS = KV dbuf 64KB + P 16KB = 80KB -> 2 blocks/CU.
// Grid (bh=64, tile=16) with qt = 15-blockIdx.y: the 512 big blocks (nkt>=5)
// dispatch first and fill all slots; small blocks backfill.
// V staged via pre-swizzled global source (m173): linear gl2lds dest + XOR'd
// source chunk == full 16-chunk XOR swizzle on read. K uses 8-chunk XOR.
#define KFRAG(tile, r, c) (*(const s8v*)&(tile)[(size_t)(r) * 64 + ((((c) ^ ((r) & 7))) << 3)])
#define VFRAG(tile, r, c) (*(const s8v*)&(tile)[(size_t)(r) * 128 + ((((c) ^ ((r) & 15))) << 3)])

__global__ __launch_bounds__(256, 2) void flash_attn_kernel(
    const unsigned short* __restrict__ q, const unsigned short* __restrict__ k,
    const unsigned short* __restrict__ vT, const unsigned short* __restrict__ mem,
    const float* __restrict__ l1, unsigned short* __restrict__ aout)
{
    const int bh = blockIdx.x;           // 0..63
    const int qt = 15 - blockIdx.y;      // big tiles dispatch first
    const int b = bh >> 3, h = bh & 7;
    const int t = threadIdx.x;
    const int w = t >> 6, lane = t & 63;
    const int quad = lane >> 4, l16 = lane & 15;
    const float lam = l1[0];

    __shared__ __align__(16) unsigned short KV[2][2][64 * 128]; // 64 KB: [buf][K/V]
    __shared__ __align__(16) unsigned short P_lds[4][16 * 128]; // 16 KB per-wave P

    const int qbase = qt * 64;
    const unsigned short* qrow = q + ((size_t)bh * kS + qbase + w * 16 + l16) * kHD;
    const s8v qa0 = *(const s8v*)(qrow + quad * 8);
    const s8v qa1 = *(const s8v*)(qrow + 32 + quad * 8);
    const unsigned short* mbase = mem + ((size_t)b * kS + qbase + w * 16 + l16) * kS;

    const unsigned short* kb = k + (size_t)bh * kS * kHD;
    const unsigned short* vb = vT + (size_t)bh * kHD * kS;

    const int nkt = (qt >> 1) + 1;       // k-tiles of 128 (max 8)

    // staging: 32 segments (16 K + 16 V) over 4 waves, 8 gl2lds per wave
    const unsigned short* gsrc[8];
    int gstep[8];
    unsigned short* ldst[8];
#pragma unroll
    for (int u = 0; u < 8; ++u) {
        const int seg = w * 8 + u;
        if (seg < 16) {                  // K seg: rows seg*8..+7 of [128][64]
            const int s = seg;
            const int rloc = s * 8 + (lane >> 3);
            const int chunk = (lane & 7) ^ ((lane >> 3) & 7);
            gsrc[u] = kb + (size_t)rloc * kHD + chunk * 8;
            gstep[u] = 128 * kHD;
            ldst[u] = &KV[0][0][s * 512];
        } else {                         // V seg: rows (d) s*4..+3 of [64][128]
            const int s = seg - 16;
            const int d = s * 4 + (lane >> 4);
            const int chunk = (lane & 15) ^ ((lane >> 4) & 3) ^ ((s & 3) << 2);
            gsrc[u] = vb + (size_t)d * kS + chunk * 8;
            gstep[u] = 128;
            ldst[u] = &KV[0][1][s * 512];
        }
    }

    // prologue: stage k-tile 0 into buffer 0
#pragma unroll
    for (int u = 0; u < 8; ++u) gl2lds(gsrc[u], ldst[u]);

    const f4v zero = {0.0f, 0.0f, 0.0f, 0.0f};
    f4v Oa[4], Om[4];
    float lr[4];
#pragma unroll
    for (int nt = 0; nt < 4; ++nt) { Oa[nt] = zero; Om[nt] = zero; lr[nt] = 0.0f; }

    for (int kt = 0; kt < nkt; ++kt) {
        __syncthreads();                 // stage(kt) landed; prev-buf reads done
        const int cur = kt & 1;
        if (kt + 1 < nkt) {
            const int boff = ((kt + 1) & 1) * 16384;
#pragma unroll
            for (int u = 0; u < 8; ++u)
                gl2lds(gsrc[u] + (size_t)(kt + 1) * gstep[u], ldst[u] + boff);
        }
        // mem fragments in MFMA-A layout: row l16, k = kt*128 + ks*32 + quad*8
        s8v ma[4];
#pragma unroll
        for (int ks = 0; ks < 4; ++ks)
            ma[ks] = *(const s8v*)(mbase + kt * 128 + ks * 32 + quad * 8);

        const unsigned short* Kc = &KV[cur][0][0];
        const unsigned short* Vc = &KV[cur][1][0];
        const bool last = (kt == nkt - 1);

        // QK^T over 128 k-positions -> p = exp(s/8), masked -> 0
#pragma unroll
        for (int ct = 0; ct < 8; ++ct) {
            const int r = ct * 16 + l16;                 // k-pos in tile
            const s8v kb0 = KFRAG(Kc, r, quad);
            const s8v kb1 = KFRAG(Kc, r, 4 + quad);
            f4v acc = zero;
            acc = __builtin_amdgcn_mfma_f32_16x16x32_bf16(qa0, kb0, acc, 0, 0, 0);
            acc = __builtin_amdgcn_mfma_f32_16x16x32_bf16(qa1, kb1, acc, 0, 0, 0);
#pragma unroll
            for (int rr = 0; rr < 4; ++rr) {
                float p = __expf(acc[rr] * 0.125f);
                if (last && (kt * 128 + r) > (qbase + w * 16 + quad * 4 + rr)) p = 0.0f;
                lr[rr] += p;
                const int pr = quad * 4 + rr;
                const int ck = ct * 2 + (l16 >> 3);      // k-chunk 0..15
                P_lds[w][pr * 128 + (((ck ^ pr) & 15) << 3) + (l16 & 7)] = f2bf(p);
            }
        }
        // P in A-layout: row l16, chunk ks*4+quad (XOR l16)
        s8v pa[4];
#pragma unroll
        for (int ks = 0; ks < 4; ++ks)
            pa[ks] = *(const s8v*)&P_lds[w][l16 * 128 + ((((ks * 4 + quad) ^ l16) & 15) << 3)];
#pragma unroll
        for (int nt = 0; nt < 4; ++nt) {
#pragma unroll
            for (int ks = 0; ks < 4; ++ks) {
                const s8v vfk = VFRAG(Vc, nt * 16 + l16, ks * 4 + quad);
                Oa[nt] = __builtin_amdgcn_mfma_f32_16x16x32_bf16(pa[ks], vfk, Oa[nt], 0, 0, 0);
                Om[nt] = __builtin_amdgcn_mfma_f32_16x16x32_bf16(ma[ks], vfk, Om[nt], 0, 0, 0);
            }
        }
    }

    // epilogue: normalize + blend
    float inv4[4];
#pragma unroll
    for (int rr = 0; rr < 4; ++rr) {
        float Z = lr[rr];
        Z += __shfl_xor(Z, 1);
        Z += __shfl_xor(Z, 2);
        Z += __shfl_xor(Z, 4);
        Z += __shfl_xor(Z, 8);
        inv4[rr] = (1.0f - lam) / Z;
    }
    const int r0 = qbase + w * 16;
#pragma unroll
    for (int nt = 0; nt < 4; ++nt)
#pragma unroll
        for (int rr = 0; rr < 4; ++rr) {
            const int i = r0 + quad * 4 + rr;
            const int d = h * kHD + nt * 16 + l16;
            aout[((size_t)b * kS + i) * kD + d] =
                f2bf(Oa[nt][rr] * inv4[rr] + lam * Om[nt][rr]);
        }
}

// ---------------- LayerNorm ----------------
__global__ __launch_bounds__(256) void ln_kernel(
    const float* __restrict__ x, const float* __restrict__ g,
    const float* __restrict__ bb, float* __restrict__ out)
{
    const int row = blockIdx.x;
    const int t = threadIdx.x;
    const float* xr = x + (size_t)row * kD;
    float a = xr[t], c = xr[t + 256];
    __shared__ float red[256];
    float s1 = a + c, s2 = a * a + c * c;
    red[t] = s1;
    __syncthreads();
    for (int s = 128; s > 0; s >>= 1) {
        if (t < s) red[t] += red[t + s];
        __syncthreads();
    }
    const float sum = red[0];
    __syncthreads();
    red[t] = s2;
    __syncthreads();
    for (int s = 128; s > 0; s >>= 1) {
        if (t < s) red[t] += red[t + s];
        __syncthreads();
    }
    const float sq = red[0];
    float mu = sum * (1.0f / kD);
    float var = sq * (1.0f / kD) - mu * mu;
    float inv = rsqrtf(var + 1e-5f);
    out[(size_t)row * kD + t]       = (a - mu) * inv * g[t] + bb[t];
    out[(size_t)row * kD + t + 256] = (c - mu) * inv * g[t + 256] + bb[t + 256];
}

extern "C" void kernel_launch(void* const* d_in, const int* in_sizes, int n_in,
                              void* d_out, int out_size, void* d_ws, size_t ws_size,
                              hipStream_t stream) {
    const float* X   = (const float*)d_in[1];   // 'inputs' feeds q,k,v (query unused)
    const float* ren = (const float*)d_in[2];
    const float* ts  = (const float*)d_in[3];
    const float* Wq = (const float*)d_in[5];  const float* bq = (const float*)d_in[6];
    const float* Wk = (const float*)d_in[7];  const float* bk = (const float*)d_in[8];
    const float* Wv = (const float*)d_in[9];  const float* bv = (const float*)d_in[10];
    const float* Wo = (const float*)d_in[11]; const float* bo = (const float*)d_in[12];
    const float* W1 = (const float*)d_in[13]; const float* b1 = (const float*)d_in[14];
    const float* lng = (const float*)d_in[15]; const float* lnb = (const float*)d_in[16];
    const float* l1 = (const float*)d_in[17];
    float* out = (float*)d_out;

    char* wsb = (char*)d_ws;
    unsigned short* Xbf    = (unsigned short*)(wsb);                  // 8 MB
    unsigned short* Wqkvbf = (unsigned short*)(wsb + (8u  << 20));    // 1.5 MB
    unsigned short* WoTbf  = (unsigned short*)(wsb + (10u << 20));    // 576x512 bf16 (0.57 MB)
    unsigned short* W1bf   = (unsigned short*)(wsb + (11u << 20));    // 0.5 MB
    unsigned short* qbf    = (unsigned short*)(wsb + (12u << 20));    // 8 MB
    unsigned short* kbf    = (unsigned short*)(wsb + (20u << 20));    // 8 MB
    unsigned short* vTbf   = (unsigned short*)(wsb + (28u << 20));    // 8 MB
    unsigned short* membf  = (unsigned short*)(wsb + (36u << 20));    // 16 MB
    unsigned short* aoutbf = (unsigned short*)(wsb + (52u << 20));    // 8 MB
    unsigned short* Wcombf = (unsigned short*)(wsb + (60u << 20));    // 0.5 MB
    float*          bcombf = (float*)        (wsb + (61u << 20));     // 2 KB

    prep_kernel<<<dim3(13377), 256, 0, stream>>>(
        X, Wq, Wk, Wv, Wo, W1, ren, ts, bo, Xbf, Wqkvbf, WoTbf, W1bf, membf);
    qkv_mfma_kernel<<<dim3(kM / 128, 13), 256, 0, stream>>>(
        Xbf, Wqkvbf, bq, bk, bv, W1bf, WoTbf, b1, qbf, kbf, vTbf, Wcombf, bcombf);
    flash_attn_kernel<<<dim3(64, 16), 256, 0, stream>>>(
        qbf, kbf, vTbf, membf, l1, aoutbf);
    gemm_final_kernel<<<dim3(kM / 128, kD / 64), 256, 0, stream>>>(
        aoutbf, Wcombf, bcombf, out);
    ln_kernel<<<dim3(kM), 256, 0, stream>>>(out, lng, lnb, out);
}